// Round 1
// baseline (5413.563 us; speedup 1.0000x reference)
//
#include <hip/hip_runtime.h>
#include <math.h>

#define NN 100000
#define NE 1600000
#define NFD 128
#define KT 8
#define MT 8
#define KM 64
#define NOUT 5
#define NSK 20
#define EPSR 0.05f

#define NB 1024          // blocks for 256-thread row-pass kernels
#define RPB 98           // ceil(NN/NB)
#define NBSINK 256       // blocks for 1024-thread sink kernels
#define RPBS 391         // ceil(NN/NBSINK)
#define NBS 25000        // spmm blocks (4 nodes per block)
#define SCAN_B 391       // ceil(NN/256)

typedef unsigned int u32;

__device__ __forceinline__ float groupmax8(float v){
  v = fmaxf(v, __shfl_xor(v,1));
  v = fmaxf(v, __shfl_xor(v,2));
  v = fmaxf(v, __shfl_xor(v,4));
  return v;
}
__device__ __forceinline__ float groupsum8(float v){
  v += __shfl_xor(v,1);
  v += __shfl_xor(v,2);
  v += __shfl_xor(v,4);
  return v;
}

// ---------------- small precompute: q, logq, w2q, tq, tt, alpha ----------------
__global__ void k_prep(const float* __restrict__ tmpl, const float* __restrict__ tf,
                       const float* __restrict__ q0, const float* __restrict__ a0,
                       float* __restrict__ qbuf){
  int l = threadIdx.x; // 0..63, l = k*8+i
  float tt = 0.f;
  for (int j=0;j<NFD;j++){ float v = tf[l*NFD+j]; tt += v*v; }
  float z = q0[l];
  float mx = groupmax8(z);
  float ex = expf(z-mx);
  float s  = groupsum8(ex);
  float q  = ex/s;
  float lq = (z-mx) - logf(s);
  float w2q=0.f, tq=0.f;
  int base = l & 56;
  #pragma unroll
  for (int m=0;m<MT;m++){
    float qm = __shfl(q, base+m);
    float tm = tmpl[l*MT+m];
    w2q += tm*tm*qm;
    tq  += tm*qm;
  }
  qbuf[l]=q; qbuf[64+l]=lq; qbuf[128+l]=w2q; qbuf[192+l]=tq; qbuf[256+l]=tt;
  if (l==0) qbuf[320] = 1.f/(1.f+expf(-a0[0]));
}

// ---------------- edge sort by src: degree, scan, scatter ----------------
__global__ void k_deg(const int* __restrict__ src, int* __restrict__ deg){
  int i = blockIdx.x*blockDim.x + threadIdx.x;
  if (i < NE) atomicAdd(&deg[src[i]], 1);
}
__global__ void k_scan1(const int* __restrict__ deg, int* __restrict__ estart, int* __restrict__ bsum){
  __shared__ int sh[256];
  int t = threadIdx.x, b = blockIdx.x, i = b*256+t;
  int v = (i<NN)? deg[i] : 0;
  sh[t] = v; __syncthreads();
  for (int off=1; off<256; off<<=1){
    int x = (t>=off)? sh[t-off] : 0;
    __syncthreads();
    sh[t] += x;
    __syncthreads();
  }
  if (i<NN) estart[i] = sh[t]-v;
  if (t==255) bsum[b] = sh[t];
}
__global__ void k_scan2(const int* __restrict__ bsum, int* __restrict__ boff){
  __shared__ int sh[512];
  int t = threadIdx.x;
  int v = (t<SCAN_B)? bsum[t] : 0;
  sh[t]=v; __syncthreads();
  for (int off=1; off<512; off<<=1){
    int x = (t>=off)? sh[t-off] : 0;
    __syncthreads();
    sh[t]+=x;
    __syncthreads();
  }
  if (t<SCAN_B) boff[t] = sh[t]-v;
}
__global__ void k_scan3(int* __restrict__ estart, const int* __restrict__ boff){
  int i = blockIdx.x*256 + threadIdx.x;
  if (i<NN) estart[i] += boff[blockIdx.x];
}
__global__ void k_scatter(const int* __restrict__ src, const int* __restrict__ dst,
                          const int* __restrict__ estart, int* __restrict__ cnt,
                          int* __restrict__ sdst){
  int i = blockIdx.x*blockDim.x + threadIdx.x;
  if (i < NE){
    int s = src[i];
    int p = estart[s] + atomicAdd(&cnt[s],1);
    sdst[p] = dst[i];
  }
}

// ---------------- Mfeat: ||x||^2 + ||tf||^2 - 2 x.tf, stored (n, 64) ----------------
__global__ void __launch_bounds__(256) k_mfeat(const float* __restrict__ x, const float* __restrict__ tf,
                        const float* __restrict__ qbuf, float* __restrict__ Mf){
  __shared__ float tfs[NFD][KM];   // [j][l], 32KB, bank-friendly on read
  __shared__ float xs[4][NFD];
  int t = threadIdx.x;
  for (int idx=t; idx<KM*NFD; idx+=256){
    int row = idx>>7, col = idx&127;
    tfs[col][row] = tf[idx];
  }
  __syncthreads();
  int w = t>>6, l = t&63;
  float tt = qbuf[256+l];
  int gw = blockIdx.x*4 + w;
  int nw = gridDim.x*4;
  for (int n=gw; n<NN; n+=nw){
    float x0 = x[n*NFD + l];
    float x1 = x[n*NFD + 64 + l];
    xs[w][l] = x0; xs[w][64+l] = x1;
    float xx = x0*x0 + x1*x1;
    xx += __shfl_xor(xx,1);  xx += __shfl_xor(xx,2);  xx += __shfl_xor(xx,4);
    xx += __shfl_xor(xx,8);  xx += __shfl_xor(xx,16); xx += __shfl_xor(xx,32);
    float acc = 0.f;
    #pragma unroll 8
    for (int j=0;j<NFD;j++) acc += xs[w][j]*tfs[j][l];
    Mf[n*KM + l] = xx + tt - 2.f*acc;
  }
}

// ---------------- cost = alpha*gw_tens + (1-alpha)*Mfeat, + sum|cost| per k ----------------
template<bool FIRST>
__global__ void __launch_bounds__(256) k_cost(const float* __restrict__ tmpl, const float* __restrict__ qbuf,
                       const int* __restrict__ deg, const float* __restrict__ CT,
                       const float* __restrict__ Mf, float* __restrict__ cost,
                       float* __restrict__ absum){
  int t = threadIdx.x, w=t>>6, l=t&63, b=blockIdx.x;
  float tm[MT];
  #pragma unroll
  for (int m=0;m<MT;m++) tm[m] = tmpl[l*MT+m];
  float w2q = qbuf[128+l];
  float tq  = qbuf[192+l];
  float alpha = qbuf[320];
  float onea = 1.f-alpha;
  int base = l&56;
  float absacc = 0.f;
  int r0=b*RPB, r1=min(r0+RPB, NN);
  for (int n=r0+w; n<r1; n+=4){
    float c1p = (float)deg[n] * (1.f/NN);
    float mf = Mf[n*KM+l];
    float gwt;
    if (FIRST){
      gwt = c1p + w2q - 2.f*c1p*tq;   // CT0 = C1p[n]*q analytically
    } else {
      float ct = CT[n*KM+l];
      float dot = 0.f;
      #pragma unroll
      for (int m=0;m<MT;m++) dot += __shfl(ct, base+m)*tm[m];
      gwt = c1p + w2q - 2.f*dot;
    }
    float c = alpha*gwt + onea*mf;
    cost[n*KM+l] = c;
    absacc += fabsf(c);
  }
  absacc = groupsum8(absacc);
  __shared__ float sh[4][64];
  sh[w][l] = absacc; __syncthreads();
  if (t<64 && (l&7)==0){
    float v = sh[0][l]+sh[1][l]+sh[2][l]+sh[3][l];
    atomicAdd(&absum[l>>3], v);
  }
}

// ---------------- fused sinkhorn iteration: f from g (regs), online-LSE partials for next g ----------------
template<bool FIRST>
__global__ void __launch_bounds__(1024) k_sink(const float* __restrict__ cost, const float* __restrict__ qbuf,
                       float* __restrict__ g, const float* __restrict__ absum,
                       float* __restrict__ partM, float* __restrict__ partS,
                       u32* __restrict__ ctr){
  int t=threadIdx.x, w=t>>6, l=t&63, b=blockIdx.x, k=l>>3;
  float e = EPSR * absum[k] * (1.f/((float)NN*MT));
  float inv_e = 1.f/e;
  const float logp = -logf((float)NN);
  float gle = FIRST ? 0.f : g[l]*inv_e;
  float mrun = -1e30f, srun = 0.f;
  int r0=b*RPBS, r1=min(r0+RPBS, NN);
  for (int n=r0+w; n<r1; n+=16){
    float c = cost[n*KM+l];
    float ce = c*inv_e;
    float xx;
    if (FIRST){
      xx = -ce;                       // f0 = 0
    } else {
      float y = gle - ce;             // (g - cost)/e
      float mx = groupmax8(y);
      float s8 = groupsum8(expf(y-mx));
      float lse = mx + logf(s8);      // f/e = logp - lse
      xx = logp - lse - ce;           // (f - cost)/e
    }
    float nm = fmaxf(mrun, xx);
    srun = srun*expf(mrun-nm) + expf(xx-nm);
    mrun = nm;
  }
  __shared__ float shm[16][64], shs[16][64];
  __shared__ int isLast;
  shm[w][l]=mrun; shs[w][l]=srun;
  __syncthreads();
  if (t<64){
    float M=shm[0][l], S=shs[0][l];
    #pragma unroll
    for (int ww=1; ww<16; ww++){
      float m2=shm[ww][l], s2=shs[ww][l];
      float nm=fmaxf(M,m2);
      S = S*expf(M-nm) + s2*expf(m2-nm);
      M = nm;
    }
    partM[l*NBSINK + b] = M;
    partS[l*NBSINK + b] = S;
  }
  __syncthreads();
  if (t==0){
    __threadfence();
    u32 prev = atomicAdd(ctr, 1u);
    isLast = (prev == gridDim.x-1);
  }
  __syncthreads();
  if (isLast){
    __threadfence();
    int ch = t>>6;   // 16 chunks of 16 blocks
    float M=-1e30f, S=0.f;
    for (int bb=ch; bb<NBSINK; bb+=16){
      float m2=partM[l*NBSINK+bb], s2=partS[l*NBSINK+bb];
      float nm=fmaxf(M,m2);
      S = S*expf(M-nm) + s2*expf(m2-nm);
      M = nm;
    }
    shm[ch][l]=M; shs[ch][l]=S;
    __syncthreads();
    if (t<64){
      float Mv=shm[0][t], Sv=shs[0][t];
      #pragma unroll
      for (int c2=1;c2<16;c2++){
        float m2=shm[c2][t], s2=shs[c2][t];
        float nm=fmaxf(Mv,m2);
        Sv = Sv*expf(Mv-nm) + s2*expf(m2-nm);
        Mv = nm;
      }
      float lse = Mv + logf(Sv);
      g[t] = e*(qbuf[64+t] - lse);   // e*logq - e*LSE (e is lane-correct: l==t)
    }
  }
}

// ---------------- T = exp((f+g-cost)/e), in place over cost ----------------
__global__ void __launch_bounds__(256) k_T(float* __restrict__ cost, const float* __restrict__ g,
                    const float* __restrict__ absum){
  int t=threadIdx.x, w=t>>6, l=t&63, b=blockIdx.x, k=l>>3;
  float e = EPSR*absum[k]*(1.f/((float)NN*MT));
  float inv_e = 1.f/e;
  const float logp = -logf((float)NN);
  float gle = g[l]*inv_e;
  int r0=b*RPB, r1=min(r0+RPB,NN);
  for (int n=r0+w; n<r1; n+=4){
    float c = cost[n*KM+l];
    float y = gle - c*inv_e;
    float mx = groupmax8(y);
    float s8 = groupsum8(expf(y-mx));
    float lse = mx + logf(s8);
    cost[n*KM+l] = expf(logp - lse + y);
  }
}

// ---------------- SPMM: CT[s,:] = sum_{e:src=s} T[dst_e,:]  (sorted edges, no atomics) ----------------
__global__ void __launch_bounds__(256) k_spmm(const float* __restrict__ T, const int* __restrict__ sdst,
                       const int* __restrict__ estart, const int* __restrict__ deg,
                       float* __restrict__ CT){
  int t=threadIdx.x, w=t>>6, l=t&63;
  int s = blockIdx.x*4 + w;
  if (s>=NN) return;
  int st = estart[s], len = deg[s];
  float acc=0.f;
  int j=0;
  for (; j+3<len; j+=4){
    int d0=sdst[st+j], d1=sdst[st+j+1], d2=sdst[st+j+2], d3=sdst[st+j+3];
    acc += T[d0*KM+l]; acc += T[d1*KM+l]; acc += T[d2*KM+l]; acc += T[d3*KM+l];
  }
  for (; j<len; j++) acc += T[sdst[st+j]*KM+l];
  CT[s*KM+l] = acc;
}

// ---------------- final fgw partials ----------------
__global__ void __launch_bounds__(256) k_fgw(const float* __restrict__ T, const float* __restrict__ Mf,
                      const float* __restrict__ CT, const int* __restrict__ deg,
                      const float* __restrict__ tmpl, const float* __restrict__ qbuf,
                      float* __restrict__ partF){
  int t=threadIdx.x, w=t>>6, l=t&63, b=blockIdx.x;
  float tm[MT];
  #pragma unroll
  for (int m=0;m<MT;m++) tm[m]=tmpl[l*MT+m];
  float w2q = qbuf[128+l];
  int base=l&56;
  float mfa=0.f, gwa=0.f;
  int r0=b*RPB, r1=min(r0+RPB,NN);
  for (int n=r0+w;n<r1;n+=4){
    float tv = T[n*KM+l];
    float mf = Mf[n*KM+l];
    float ct = CT[n*KM+l];
    float c1p = (float)deg[n]*(1.f/NN);
    float dot=0.f;
    #pragma unroll
    for (int m=0;m<MT;m++) dot += __shfl(ct, base+m)*tm[m];
    float tens = c1p + w2q - 2.f*dot;
    mfa += mf*tv;
    gwa += tens*tv;
  }
  mfa = groupsum8(mfa); gwa = groupsum8(gwa);
  __shared__ float sh[4][64], sh2[4][64];
  sh[w][l]=mfa; sh2[w][l]=gwa; __syncthreads();
  if (t<64 && (l&7)==0){
    float vm = sh[0][l]+sh[1][l]+sh[2][l]+sh[3][l];
    float vg = sh2[0][l]+sh2[1][l]+sh2[2][l]+sh2[3][l];
    partF[b*16 + (l>>3)]     = vm;
    partF[b*16 + 8 + (l>>3)] = vg;
  }
}

__global__ void k_out(const float* __restrict__ partF, const float* __restrict__ qbuf,
                      float* __restrict__ out){
  __shared__ double sd[16][16];
  __shared__ float fin[16];
  int t=threadIdx.x;
  int o=t&15, ch=t>>4;
  double s=0.0;
  for (int bb=ch; bb<NB; bb+=16) s += (double)partF[bb*16+o];
  sd[ch][o]=s; __syncthreads();
  if (t<16){
    double v=0.0;
    for (int c=0;c<16;c++) v += sd[c][t];
    fin[t]=(float)v;
  }
  __syncthreads();
  if (t<8){
    float alpha = qbuf[320];
    out[t] = (1.f-alpha)*fin[t] + alpha*fin[8+t];
  }
}

extern "C" void kernel_launch(void* const* d_in, const int* in_sizes, int n_in,
                              void* d_out, int out_size, void* d_ws, size_t ws_size,
                              hipStream_t stream){
  const float* x    = (const float*)d_in[0];
  const int*   ei   = (const int*)  d_in[1];
  const float* tmpl = (const float*)d_in[2];
  const float* tf   = (const float*)d_in[3];
  const float* q0   = (const float*)d_in[4];
  const float* a0   = (const float*)d_in[5];
  const int* src = ei;
  const int* dst = ei + NE;

  char* ws = (char*)d_ws;
  size_t o=0;
  auto carve = [&](size_t bytes)->void*{ void* p = ws+o; o += (bytes+255)&~(size_t)255; return p; };
  float* costT = (float*)carve((size_t)NN*KM*4);   // cost, overwritten by T in place
  float* CT    = (float*)carve((size_t)NN*KM*4);
  float* Mf    = (float*)carve((size_t)NN*KM*4);
  int* sdst    = (int*)carve((size_t)NE*4);
  int* deg     = (int*)carve((size_t)NN*4);
  int* estart  = (int*)carve((size_t)NN*4);
  int* cnt     = (int*)carve((size_t)NN*4);
  int* bsum    = (int*)carve(512*4);
  int* boff    = (int*)carve(512*4);
  float* qbuf  = (float*)carve(512*4);
  float* gbuf  = (float*)carve(64*4);
  float* absum = (float*)carve(64*4);              // 5 outer * 8 k
  u32* ctr     = (u32*)carve(128*4);
  float* partM = (float*)carve((size_t)KM*NBSINK*4);
  float* partS = (float*)carve((size_t)KM*NBSINK*4);
  float* partF = (float*)carve((size_t)NB*16*4);

  hipMemsetAsync(deg,   0, NN*4,  stream);
  hipMemsetAsync(cnt,   0, NN*4,  stream);
  hipMemsetAsync(absum, 0, 64*4,  stream);
  hipMemsetAsync(ctr,   0, 128*4, stream);

  k_prep<<<1,64,0,stream>>>(tmpl, tf, q0, a0, qbuf);
  k_deg<<<(NE+255)/256,256,0,stream>>>(src, deg);
  k_scan1<<<SCAN_B,256,0,stream>>>(deg, estart, bsum);
  k_scan2<<<1,512,0,stream>>>(bsum, boff);
  k_scan3<<<SCAN_B,256,0,stream>>>(estart, boff);
  k_scatter<<<(NE+255)/256,256,0,stream>>>(src, dst, estart, cnt, sdst);
  k_mfeat<<<512,256,0,stream>>>(x, tf, qbuf, Mf);

  for (int it=0; it<NOUT; it++){
    float* as = absum + it*8;
    if (it==0) k_cost<true ><<<NB,256,0,stream>>>(tmpl,qbuf,deg,CT,Mf,costT,as);
    else       k_cost<false><<<NB,256,0,stream>>>(tmpl,qbuf,deg,CT,Mf,costT,as);
    k_sink<true ><<<NBSINK,1024,0,stream>>>(costT,qbuf,gbuf,as,partM,partS,ctr+it*20);
    for (int j=1;j<NSK;j++)
      k_sink<false><<<NBSINK,1024,0,stream>>>(costT,qbuf,gbuf,as,partM,partS,ctr+it*20+j);
    k_T<<<NB,256,0,stream>>>(costT,gbuf,as);
    k_spmm<<<NBS,256,0,stream>>>(costT,sdst,estart,deg,CT);
  }
  k_fgw<<<NB,256,0,stream>>>(costT,Mf,CT,deg,tmpl,qbuf,partF);
  k_out<<<1,256,0,stream>>>(partF,qbuf,(float*)d_out);
}

// Round 2
// 3270.729 us; speedup vs baseline: 1.6552x; 1.6552x over previous
//
#include <hip/hip_runtime.h>
#include <math.h>

#define NN 100000
#define NE 1600000
#define NFD 128
#define KT 8
#define MT 8
#define KM 64
#define NOUT 5
#define NSK 20
#define EPSR 0.05f

#define NBLK 248          // persistent blocks, 1 per CU (112KB LDS forces 1/CU; 248<=256 -> all co-resident)
#define RPBM 404          // ceil(NN/NBLK); 248*404 = 100192
#define SCAN_B 391        // ceil(NN/256)

typedef unsigned int u32;

__device__ __forceinline__ float groupmax8(float v){
  v = fmaxf(v, __shfl_xor(v,1));
  v = fmaxf(v, __shfl_xor(v,2));
  v = fmaxf(v, __shfl_xor(v,4));
  return v;
}
__device__ __forceinline__ float groupsum8(float v){
  v += __shfl_xor(v,1);
  v += __shfl_xor(v,2);
  v += __shfl_xor(v,4);
  return v;
}
__device__ __forceinline__ float ex2(float x){ return __builtin_amdgcn_exp2f(x); }
__device__ __forceinline__ float lg2(float x){ return __builtin_amdgcn_logf(x); }   // log2

// grid-wide barrier: device-scope arrive counter + generation flag.
// release fence (buffer_wbl2) makes this block's writes visible device-wide;
// acquire fence (buffer_inv) invalidates stale L1/L2 so plain loads after the
// barrier are correct across XCDs.
__device__ __forceinline__ void gridbar(u32* cnt, u32* gen){
  __syncthreads();
  if (threadIdx.x==0){
    __builtin_amdgcn_fence(__ATOMIC_RELEASE, "agent");
    u32 g = __hip_atomic_load(gen, __ATOMIC_RELAXED, __HIP_MEMORY_SCOPE_AGENT);
    u32 old = __hip_atomic_fetch_add(cnt, 1u, __ATOMIC_RELAXED, __HIP_MEMORY_SCOPE_AGENT);
    if (old == (u32)(NBLK-1)){
      __hip_atomic_store(cnt, 0u, __ATOMIC_RELAXED, __HIP_MEMORY_SCOPE_AGENT);
      __hip_atomic_store(gen, g+1u, __ATOMIC_RELEASE, __HIP_MEMORY_SCOPE_AGENT);
    } else {
      long sp = 0;
      while (__hip_atomic_load(gen, __ATOMIC_RELAXED, __HIP_MEMORY_SCOPE_AGENT) == g){
        __builtin_amdgcn_s_sleep(1);
        if (++sp > (1L<<24)) break;   // safety valve: never hang the container
      }
    }
    __builtin_amdgcn_fence(__ATOMIC_ACQUIRE, "agent");
  }
  __syncthreads();
}

// ---------------- small precompute: q, logq, w2q, tq, alpha ----------------
__global__ void k_prep(const float* __restrict__ tmpl, const float* __restrict__ tf,
                       const float* __restrict__ q0, const float* __restrict__ a0,
                       float* __restrict__ qbuf){
  int l = threadIdx.x; // 0..63, l = k*8+i
  float z = q0[l];
  float mx = groupmax8(z);
  float ex = expf(z-mx);
  float s  = groupsum8(ex);
  float q  = ex/s;
  float lq = (z-mx) - logf(s);
  float w2q=0.f, tq=0.f;
  int base = l & 56;
  #pragma unroll
  for (int m=0;m<MT;m++){
    float qm = __shfl(q, base+m);
    float tm = tmpl[l*MT+m];
    w2q += tm*tm*qm;
    tq  += tm*qm;
  }
  qbuf[l]=q; qbuf[64+l]=lq; qbuf[128+l]=w2q; qbuf[192+l]=tq;
  if (l==0) qbuf[320] = 1.f/(1.f+expf(-a0[0]));
}

// ---------------- edge sort by src: degree, scan, scatter ----------------
__global__ void k_deg(const int* __restrict__ src, int* __restrict__ deg){
  int i = blockIdx.x*blockDim.x + threadIdx.x;
  if (i < NE) atomicAdd(&deg[src[i]], 1);
}
__global__ void k_scan1(const int* __restrict__ deg, int* __restrict__ estart, int* __restrict__ bsum){
  __shared__ int sh[256];
  int t = threadIdx.x, b = blockIdx.x, i = b*256+t;
  int v = (i<NN)? deg[i] : 0;
  sh[t] = v; __syncthreads();
  for (int off=1; off<256; off<<=1){
    int x = (t>=off)? sh[t-off] : 0;
    __syncthreads();
    sh[t] += x;
    __syncthreads();
  }
  if (i<NN) estart[i] = sh[t]-v;
  if (t==255) bsum[b] = sh[t];
}
__global__ void k_scan2(const int* __restrict__ bsum, int* __restrict__ boff){
  __shared__ int sh[512];
  int t = threadIdx.x;
  int v = (t<SCAN_B)? bsum[t] : 0;
  sh[t]=v; __syncthreads();
  for (int off=1; off<512; off<<=1){
    int x = (t>=off)? sh[t-off] : 0;
    __syncthreads();
    sh[t]+=x;
    __syncthreads();
  }
  if (t<SCAN_B) boff[t] = sh[t]-v;
}
__global__ void k_scan3(int* __restrict__ estart, const int* __restrict__ boff){
  int i = blockIdx.x*256 + threadIdx.x;
  if (i<NN) estart[i] += boff[blockIdx.x];
}
__global__ void k_scatter(const int* __restrict__ src, const int* __restrict__ dst,
                          const int* __restrict__ estart, int* __restrict__ cnt,
                          int* __restrict__ sdst){
  int i = blockIdx.x*blockDim.x + threadIdx.x;
  if (i < NE){
    int s = src[i];
    int p = estart[s] + atomicAdd(&cnt[s],1);
    sdst[p] = dst[i];
  }
}

// ---------------- Mfeat: tf columns in VGPRs, x broadcast via readlane ----------------
__global__ void __launch_bounds__(256,2) k_mfeat(const float* __restrict__ x,
                                                 const float* __restrict__ tf,
                                                 float* __restrict__ Mf){
  int t=threadIdx.x, w=t>>6, l=t&63;
  float tfr[NFD];
  #pragma unroll
  for (int j=0;j<NFD;j++) tfr[j]=tf[l*NFD+j];
  float tt=0.f;
  #pragma unroll
  for (int j=0;j<NFD;j++) tt += tfr[j]*tfr[j];
  int gw=blockIdx.x*4+w, nw=gridDim.x*4;
  for (int n=gw; n<NN; n+=nw){
    float x0=x[(size_t)n*NFD+l], x1=x[(size_t)n*NFD+64+l];
    float acc=0.f;
    #pragma unroll
    for (int j=0;j<64;j++){
      float xa=__builtin_bit_cast(float, __builtin_amdgcn_readlane(__builtin_bit_cast(int,x0), j));
      float xb=__builtin_bit_cast(float, __builtin_amdgcn_readlane(__builtin_bit_cast(int,x1), j));
      acc = fmaf(xa, tfr[j], acc);
      acc = fmaf(xb, tfr[64+j], acc);
    }
    float xx=x0*x0+x1*x1;
    xx+=__shfl_xor(xx,1); xx+=__shfl_xor(xx,2); xx+=__shfl_xor(xx,4);
    xx+=__shfl_xor(xx,8); xx+=__shfl_xor(xx,16); xx+=__shfl_xor(xx,32);
    Mf[(size_t)n*KM+l]=xx+tt-2.f*acc;
  }
}

// ---------------- the persistent fused kernel: cost -> 20x sinkhorn -> T -> spmm, x5, + fgw ----------------
__global__ void __launch_bounds__(1024,4) k_main(
    const float* __restrict__ tmpl, const float* __restrict__ qbuf,
    const int* __restrict__ deg, const int* __restrict__ estart,
    const int* __restrict__ sdst, const float* __restrict__ Mf,
    float* __restrict__ CT, float* __restrict__ Tg, float2* __restrict__ pb,
    float* __restrict__ absum, float* __restrict__ fgwacc,
    u32* __restrict__ cnt, u32* __restrict__ gen, float* __restrict__ outp)
{
  __shared__ float cls[RPBM*KM];   // 103,424 B: this block's cost/T slice
  __shared__ float shm[16*64];
  __shared__ float shs[16*64];
  __shared__ float gsh[64];

  const int t = threadIdx.x, w = t>>6, l = t&63, b = blockIdx.x;
  const int base = l&56;
  const int n0 = b*RPBM;
  const int nrows = min(RPBM, NN-n0);
  const float LOG2E = 1.4426950408889634f;
  const float logp2 = -log2f((float)NN);

  float tm[MT];
  #pragma unroll
  for (int m=0;m<MT;m++) tm[m]=tmpl[l*MT+m];
  const float w2q=qbuf[128+l], tq=qbuf[192+l], lq=qbuf[64+l], alpha=qbuf[320];
  const float onea = 1.f-alpha;

  for (int it=0; it<NOUT; ++it){
    // ---- A: cost into LDS + per-k mean|cost| ----
    float absacc=0.f;
    for (int rr=w; rr<nrows; rr+=16){
      int n=n0+rr;
      float c1p = (float)deg[n]*(1.f/NN);
      float mf = Mf[(size_t)n*KM+l];
      float gwt;
      if (it==0){
        gwt = c1p + w2q - 2.f*c1p*tq;          // CT0 = C1p[n]*q analytically
      } else {
        float ct = CT[(size_t)n*KM+l];
        float dot=0.f;
        #pragma unroll
        for(int m=0;m<MT;m++) dot += __shfl(ct, base+m)*tm[m];
        gwt = c1p + w2q - 2.f*dot;
      }
      float c = alpha*gwt + onea*mf;
      cls[rr*KM+l]=c;
      absacc += fabsf(c);
    }
    absacc = groupsum8(absacc);
    __syncthreads();
    shm[w*64+l]=absacc;
    __syncthreads();
    if (t<64 && (l&7)==0){
      float v=0.f;
      #pragma unroll
      for(int ww=0;ww<16;ww++) v+=shm[ww*64+l];
      atomicAdd(&absum[it*8+(l>>3)], v);
    }
    gridbar(cnt,gen);
    float e = EPSR * absum[it*8+(l>>3)] * (1.f/((float)NN*MT));
    float ie2 = LOG2E/e;
    // A2: pre-scale cost to base-2 units (c2 = c/e * log2e)
    for (int rr=w; rr<nrows; rr+=16) cls[rr*KM+l] *= ie2;
    __syncthreads();

    // ---- B: 20 fused sinkhorn iterations (cost lives in LDS) ----
    float gl2 = 0.f;   // g[l]/e in base-2 units
    for (int j=0;j<NSK;j++){
      float mrun=-3e38f, srun=0.f;
      for (int rr=w; rr<nrows; rr+=16){
        float c2 = cls[rr*KM+l];
        float xx;
        if (j==0){
          xx = -c2;                              // f0 = 0
        } else {
          float y = gl2 - c2;                    // (g - c)/e, base-2
          float mx = groupmax8(y);
          float s8 = groupsum8(ex2(y-mx));
          float lse = mx + lg2(s8);              // f/e (base2) = logp2 - lse
          xx = logp2 - lse - c2;                 // (f - c)/e, base-2
        }
        if (xx <= mrun){ srun += ex2(xx-mrun); }
        else { srun = srun*ex2(mrun-xx) + 1.f; mrun=xx; }
      }
      // intra-block online-LSE combine (16 waves)
      __syncthreads();
      shm[w*64+l]=mrun; shs[w*64+l]=srun;
      __syncthreads();
      if (t<64){
        float M=shm[l], S=shs[l];
        #pragma unroll
        for(int ww=1;ww<16;ww++){
          float m2=shm[ww*64+l], s2=shs[ww*64+l];
          float nm=fmaxf(M,m2);
          S = S*ex2(M-nm) + s2*ex2(m2-nm);
          M = nm;
        }
        pb[(size_t)(j&1)*NBLK*KM + (size_t)b*KM + l] = make_float2(M,S);
      }
      gridbar(cnt,gen);
      // redundant cross-block combine (every block computes g itself; no 2nd barrier)
      {
        const float2* src = pb + (size_t)(j&1)*NBLK*KM;
        float M=-3e38f, S=0.f;
        for (int bb=w; bb<NBLK; bb+=16){        // wave w reads rows bb=w,w+16,... : 512B coalesced
          float2 v = src[(size_t)bb*KM + l];
          float nm=fmaxf(M,v.x);
          S = S*ex2(M-nm) + v.y*ex2(v.x-nm);
          M = nm;
        }
        shm[w*64+l]=M; shs[w*64+l]=S;
        __syncthreads();
        if (t<64){
          float M2=shm[l], S2=shs[l];
          #pragma unroll
          for(int ww=1;ww<16;ww++){
            float m2=shm[ww*64+l], s2=shs[ww*64+l];
            float nm=fmaxf(M2,m2);
            S2 = S2*ex2(M2-nm) + s2*ex2(m2-nm);
            M2 = nm;
          }
          float lse2 = M2 + lg2(S2);
          gsh[l] = lq*LOG2E - lse2;              // g/e in base-2 units
        }
        __syncthreads();
        gl2 = gsh[l];
      }
    }

    // ---- C: T = 2^(logp2 - lse_row + y), into LDS (in place) + global for the gather ----
    for (int rr=w; rr<nrows; rr+=16){
      int n=n0+rr;
      float c2 = cls[rr*KM+l];
      float y = gl2 - c2;
      float mx = groupmax8(y);
      float s8 = groupsum8(ex2(y-mx));
      float lse = mx + lg2(s8);
      float tv = ex2(logp2 - lse + y);
      cls[rr*KM+l] = tv;
      Tg[(size_t)n*KM+l] = tv;
    }
    gridbar(cnt,gen);

    // ---- D: SPMM over own rows (sorted edges, no atomics) ----
    for (int rr=w; rr<nrows; rr+=16){
      int s = n0+rr;
      int st=estart[s], len=deg[s];
      float acc=0.f;
      int jj=0;
      for (; jj+3<len; jj+=4){
        int d0=sdst[st+jj], d1=sdst[st+jj+1], d2=sdst[st+jj+2], d3=sdst[st+jj+3];
        acc += Tg[(size_t)d0*KM+l]; acc += Tg[(size_t)d1*KM+l];
        acc += Tg[(size_t)d2*KM+l]; acc += Tg[(size_t)d3*KM+l];
      }
      for (; jj<len; jj++) acc += Tg[(size_t)sdst[st+jj]*KM+l];
      CT[(size_t)s*KM+l] = acc;
    }
    gridbar(cnt,gen);
  }

  // ---- E: fgw reduction (T of last outer still in LDS) ----
  float mfa=0.f, gwa=0.f;
  for (int rr=w; rr<nrows; rr+=16){
    int n=n0+rr;
    float tv = cls[rr*KM+l];
    float mf = Mf[(size_t)n*KM+l];
    float ct = CT[(size_t)n*KM+l];
    float c1p=(float)deg[n]*(1.f/NN);
    float dot=0.f;
    #pragma unroll
    for(int m=0;m<MT;m++) dot += __shfl(ct, base+m)*tm[m];
    float tens = c1p + w2q - 2.f*dot;
    mfa += mf*tv; gwa += tens*tv;
  }
  mfa=groupsum8(mfa); gwa=groupsum8(gwa);
  __syncthreads();
  shm[w*64+l]=mfa; shs[w*64+l]=gwa;
  __syncthreads();
  if (t<64 && (l&7)==0){
    float vm=0.f, vg=0.f;
    #pragma unroll
    for(int ww=0;ww<16;ww++){ vm+=shm[ww*64+l]; vg+=shs[ww*64+l]; }
    atomicAdd(&fgwacc[l>>3], vm);
    atomicAdd(&fgwacc[8+(l>>3)], vg);
  }
  gridbar(cnt,gen);
  if (b==0 && t<8){
    outp[t] = onea*fgwacc[t] + alpha*fgwacc[8+t];
  }
}

extern "C" void kernel_launch(void* const* d_in, const int* in_sizes, int n_in,
                              void* d_out, int out_size, void* d_ws, size_t ws_size,
                              hipStream_t stream){
  const float* x    = (const float*)d_in[0];
  const int*   ei   = (const int*)  d_in[1];
  const float* tmpl = (const float*)d_in[2];
  const float* tf   = (const float*)d_in[3];
  const float* q0   = (const float*)d_in[4];
  const float* a0   = (const float*)d_in[5];
  const int* src = ei;
  const int* dst = ei + NE;

  char* ws = (char*)d_ws;
  size_t o=0;
  auto carve = [&](size_t bytes)->void*{ void* p = ws+o; o += (bytes+255)&~(size_t)255; return p; };
  float* Tg    = (float*)carve((size_t)NN*KM*4);
  float* CT    = (float*)carve((size_t)NN*KM*4);
  float* Mf    = (float*)carve((size_t)NN*KM*4);
  int* sdst    = (int*)carve((size_t)NE*4);
  int* deg     = (int*)carve((size_t)NN*4);
  int* estart  = (int*)carve((size_t)NN*4);
  int* scnt    = (int*)carve((size_t)NN*4);
  int* bsum    = (int*)carve(512*4);
  int* boff    = (int*)carve(512*4);
  float* qbuf  = (float*)carve(512*4);
  float* absum = (float*)carve(64*4);
  float* fgwacc= (float*)carve(64*4);
  u32* sync    = (u32*)carve(256);
  float2* pb   = (float2*)carve((size_t)2*NBLK*KM*sizeof(float2));

  hipMemsetAsync(deg,    0, NN*4,  stream);
  hipMemsetAsync(scnt,   0, NN*4,  stream);
  hipMemsetAsync(absum,  0, 64*4,  stream);
  hipMemsetAsync(fgwacc, 0, 64*4,  stream);
  hipMemsetAsync(sync,   0, 256,   stream);

  k_prep<<<1,64,0,stream>>>(tmpl, tf, q0, a0, qbuf);
  k_deg<<<(NE+255)/256,256,0,stream>>>(src, deg);
  k_scan1<<<SCAN_B,256,0,stream>>>(deg, estart, bsum);
  k_scan2<<<1,512,0,stream>>>(bsum, boff);
  k_scan3<<<SCAN_B,256,0,stream>>>(estart, boff);
  k_scatter<<<(NE+255)/256,256,0,stream>>>(src, dst, estart, scnt, sdst);
  k_mfeat<<<512,256,0,stream>>>(x, tf, Mf);

  k_main<<<NBLK,1024,0,stream>>>(tmpl, qbuf, deg, estart, sdst, Mf,
                                 CT, Tg, pb, absum, fgwacc,
                                 sync, sync+64, (float*)d_out);
}

// Round 6
// 3131.706 us; speedup vs baseline: 1.7286x; 1.0444x over previous
//
#include <hip/hip_runtime.h>
#include <math.h>

#define NN 100000
#define NE 1600000
#define NFD 128
#define KT 8
#define MT 8
#define KM 64
#define NOUT 5
#define NSK 20
#define EPSR 0.05f

#define NBLK 248          // persistent blocks, 1 per CU (112KB LDS forces 1/CU)
#define RPBM 404          // ceil(NN/NBLK)
#define SLOTS 26          // ceil(RPBM/16)
#define SCAN_B 391        // ceil(NN/256)

typedef unsigned int u32;
typedef unsigned long long u64;

__device__ __forceinline__ float groupmax8(float v){
  v = fmaxf(v, __shfl_xor(v,1));
  v = fmaxf(v, __shfl_xor(v,2));
  v = fmaxf(v, __shfl_xor(v,4));
  return v;
}
__device__ __forceinline__ float groupsum8(float v){
  v += __shfl_xor(v,1);
  v += __shfl_xor(v,2);
  v += __shfl_xor(v,4);
  return v;
}
__device__ __forceinline__ float ex2(float x){ return __builtin_amdgcn_exp2f(x); }
__device__ __forceinline__ float lg2(float x){ return __builtin_amdgcn_logf(x); }   // log2

__device__ __forceinline__ u64 packMS(float M, float S){
  return ((u64)__builtin_bit_cast(u32, S) << 32) | (u64)__builtin_bit_cast(u32, M);
}
__device__ __forceinline__ float unpackM(u64 v){ return __builtin_bit_cast(float, (u32)(v & 0xffffffffull)); }
__device__ __forceinline__ float unpackS(u64 v){ return __builtin_bit_cast(float, (u32)(v >> 32)); }

// Contention-free grid barrier: per-block monotonic epoch flags (no same-address
// RMW). Light version relies on participants using agent-scope (LLC-coherent)
// atomics for the data they exchange; full version adds agent release/acquire
// fences (wbl2/inv) for bulk plain-store data (Tg).
__device__ __forceinline__ void gbar(u32* __restrict__ flags, u32 tgt, bool full){
  asm volatile("s_waitcnt vmcnt(0)" ::: "memory");   // this wave's stores/atomics complete
  __syncthreads();                                    // all waves drained
  const int t = threadIdx.x;
  if (t==0){
    if (full) __builtin_amdgcn_fence(__ATOMIC_RELEASE, "agent");   // wbl2: flush dirty L2
    __hip_atomic_store(&flags[blockIdx.x], tgt, __ATOMIC_RELAXED, __HIP_MEMORY_SCOPE_AGENT);
  }
  if (t < NBLK){
    int sp = 0;
    while (__hip_atomic_load(&flags[t], __ATOMIC_RELAXED, __HIP_MEMORY_SCOPE_AGENT) < tgt){
      __builtin_amdgcn_s_sleep(2);
      if (++sp > (1<<20)) break;   // safety valve
    }
  }
  __syncthreads();
  if (full){
    if (t==0) __builtin_amdgcn_fence(__ATOMIC_ACQUIRE, "agent");   // inv L1/L2
    __syncthreads();
  }
}

// ---------------- small precompute: q, logq, w2q, tq, alpha ----------------
__global__ void k_prep(const float* __restrict__ tmpl, const float* __restrict__ tf,
                       const float* __restrict__ q0, const float* __restrict__ a0,
                       float* __restrict__ qbuf){
  int l = threadIdx.x; // 0..63, l = k*8+i
  float z = q0[l];
  float mx = groupmax8(z);
  float ex = expf(z-mx);
  float s  = groupsum8(ex);
  float q  = ex/s;
  float lq = (z-mx) - logf(s);
  float w2q=0.f, tq=0.f;
  int base = l & 56;
  #pragma unroll
  for (int m=0;m<MT;m++){
    float qm = __shfl(q, base+m);
    float tm = tmpl[l*MT+m];
    w2q += tm*tm*qm;
    tq  += tm*qm;
  }
  qbuf[l]=q; qbuf[64+l]=lq; qbuf[128+l]=w2q; qbuf[192+l]=tq;
  if (l==0) qbuf[320] = 1.f/(1.f+expf(-a0[0]));
}

// ---------------- edge CSR build: deg+rank, scan, scatter (no scatter atomics) ----------------
__global__ void k_deg(const int* __restrict__ src, int* __restrict__ deg, int* __restrict__ rank){
  int i = blockIdx.x*blockDim.x + threadIdx.x;
  if (i < NE) rank[i] = atomicAdd(&deg[src[i]], 1);
}
__global__ void k_scan1(const int* __restrict__ deg, int* __restrict__ estart, int* __restrict__ bsum){
  __shared__ int sh[256];
  int t = threadIdx.x, b = blockIdx.x, i = b*256+t;
  int v = (i<NN)? deg[i] : 0;
  sh[t] = v; __syncthreads();
  for (int off=1; off<256; off<<=1){
    int x = (t>=off)? sh[t-off] : 0;
    __syncthreads();
    sh[t] += x;
    __syncthreads();
  }
  if (i<NN) estart[i] = sh[t]-v;
  if (t==255) bsum[b] = sh[t];
}
__global__ void k_scan2(const int* __restrict__ bsum, int* __restrict__ boff){
  __shared__ int sh[512];
  int t = threadIdx.x;
  int v = (t<SCAN_B)? bsum[t] : 0;
  sh[t]=v; __syncthreads();
  for (int off=1; off<512; off<<=1){
    int x = (t>=off)? sh[t-off] : 0;
    __syncthreads();
    sh[t]+=x;
    __syncthreads();
  }
  if (t<SCAN_B) boff[t] = sh[t]-v;
}
__global__ void k_scan3(int* __restrict__ estart, const int* __restrict__ boff){
  int i = blockIdx.x*256 + threadIdx.x;
  if (i<NN) estart[i] += boff[blockIdx.x];
}
__global__ void k_scatter(const int* __restrict__ src, const int* __restrict__ dst,
                          const int* __restrict__ estart, const int* __restrict__ rank,
                          int* __restrict__ sdst){
  int i = blockIdx.x*blockDim.x + threadIdx.x;
  if (i < NE){
    sdst[estart[src[i]] + rank[i]] = dst[i];
  }
}

// ---------------- Mfeat: tf columns in VGPRs, x broadcast via readlane ----------------
__global__ void __launch_bounds__(256,2) k_mfeat(const float* __restrict__ x,
                                                 const float* __restrict__ tf,
                                                 float* __restrict__ Mf){
  int t=threadIdx.x, w=t>>6, l=t&63;
  float tfr[NFD];
  #pragma unroll
  for (int j=0;j<NFD;j++) tfr[j]=tf[l*NFD+j];
  float tt=0.f;
  #pragma unroll
  for (int j=0;j<NFD;j++) tt += tfr[j]*tfr[j];
  int gw=blockIdx.x*4+w, nw=gridDim.x*4;
  for (int n=gw; n<NN; n+=nw){
    float x0=x[(size_t)n*NFD+l], x1=x[(size_t)n*NFD+64+l];
    float acc=0.f;
    #pragma unroll
    for (int j=0;j<64;j++){
      float xa=__builtin_bit_cast(float, __builtin_amdgcn_readlane(__builtin_bit_cast(int,x0), j));
      float xb=__builtin_bit_cast(float, __builtin_amdgcn_readlane(__builtin_bit_cast(int,x1), j));
      acc = fmaf(xa, tfr[j], acc);
      acc = fmaf(xb, tfr[64+j], acc);
    }
    float xx=x0*x0+x1*x1;
    xx+=__shfl_xor(xx,1); xx+=__shfl_xor(xx,2); xx+=__shfl_xor(xx,4);
    xx+=__shfl_xor(xx,8); xx+=__shfl_xor(xx,16); xx+=__shfl_xor(xx,32);
    Mf[(size_t)n*KM+l]=xx+tt-2.f*acc;
  }
}

// ---------------- persistent fused kernel: cost -> 20x sinkhorn -> T -> spmm, x5, + fgw ----------------
__global__ void __launch_bounds__(1024,4) k_main(
    const float* __restrict__ tmpl, const float* __restrict__ qbuf,
    const int* __restrict__ deg, const int* __restrict__ estart,
    const int* __restrict__ sdst, const float* __restrict__ Mf,
    float* __restrict__ Tg, u64* __restrict__ pb,
    float* __restrict__ absum, float* __restrict__ fgwacc,
    u32* __restrict__ flags, float* __restrict__ outp)
{
  __shared__ float cls[RPBM*KM];   // 103,424 B: this block's cost/T slice
  __shared__ float shm[16*64];
  __shared__ float shs[16*64];
  __shared__ float gsh[64];

  const int t = threadIdx.x, w = t>>6, l = t&63, b = blockIdx.x;
  const int base = l&56;
  const int n0 = b*RPBM;
  const int nrows = min(RPBM, NN-n0);
  const float LOG2E = 1.4426950408889634f;
  const float logp2 = -log2f((float)NN);
  u32 bar = 0;

  float tm[MT];
  #pragma unroll
  for (int m=0;m<MT;m++) tm[m]=tmpl[l*MT+m];
  const float w2q=qbuf[128+l], tq=qbuf[192+l], lq2=qbuf[64+l]*LOG2E, alpha=qbuf[320];
  const float onea = 1.f-alpha;

  float ctreg[SLOTS];              // CT values for this thread's (row-slot, lane) pairs
  #pragma unroll
  for (int s=0;s<SLOTS;s++) ctreg[s]=0.f;

  for (int it=0; it<NOUT; ++it){
    // ---- A: cost into LDS + per-k sum|cost| ----
    float absacc=0.f;
    #pragma unroll
    for (int s=0;s<SLOTS;s++){
      int rr = w + 16*s;
      if (rr < nrows){
        int n = n0+rr;
        float c1p = (float)deg[n]*(1.f/NN);
        float mf = Mf[(size_t)n*KM+l];
        float gwt;
        if (it==0){
          gwt = c1p + w2q - 2.f*c1p*tq;          // CT0 = C1p[n]*q analytically
        } else {
          float ct = ctreg[s];
          float dot=0.f;
          #pragma unroll
          for(int m=0;m<MT;m++) dot += __shfl(ct, base+m)*tm[m];
          gwt = c1p + w2q - 2.f*dot;
        }
        float c = alpha*gwt + onea*mf;
        cls[rr*KM+l]=c;
        absacc += fabsf(c);
      }
    }
    absacc = groupsum8(absacc);
    __syncthreads();
    shm[w*64+l]=absacc;
    __syncthreads();
    if (t<64 && (l&7)==0){
      float v=0.f;
      #pragma unroll
      for(int ww=0;ww<16;ww++) v+=shm[ww*64+l];
      atomicAdd(&absum[it*8+(l>>3)], v);
    }
    gbar(flags, ++bar, false);
    float e = EPSR * __hip_atomic_load(&absum[it*8+(l>>3)], __ATOMIC_RELAXED, __HIP_MEMORY_SCOPE_AGENT)
                   * (1.f/((float)NN*MT));
    float ie2 = LOG2E/e;
    // rescale own elements to base-2 units (owner-thread only -> no sync needed)
    #pragma unroll
    for (int s=0;s<SLOTS;s++){
      int rr = w + 16*s;
      if (rr < nrows) cls[rr*KM+l] *= ie2;
    }

    // ---- B: 20 fused sinkhorn iterations ----
    float gl2 = 0.f;   // g[l]/e in base-2 units
    for (int j=0;j<NSK;j++){
      float mrun=-3e38f, srun=0.f;
      if (j==0){
        #pragma unroll
        for (int s=0;s<SLOTS;s++){
          int rr = w + 16*s;
          if (rr < nrows){
            float xx = -cls[rr*KM+l];            // f0 = 0
            float nm = fmaxf(mrun, xx);
            srun = srun*ex2(mrun-nm) + ex2(xx-nm);
            mrun = nm;
          }
        }
      } else {
        #pragma unroll
        for (int s=0;s<SLOTS;s++){
          int rr = w + 16*s;
          if (rr < nrows){
            float c2 = cls[rr*KM+l];
            float y = gl2 - c2;
            float mx = groupmax8(y);
            float s8 = groupsum8(ex2(y-mx));
            float xx = logp2 - (mx+lg2(s8)) - c2;
            float nm = fmaxf(mrun, xx);
            srun = srun*ex2(mrun-nm) + ex2(xx-nm);
            mrun = nm;
          }
        }
      }
      // intra-block combine (16 waves)
      __syncthreads();
      shm[w*64+l]=mrun; shs[w*64+l]=srun;
      __syncthreads();
      if (t<64){
        float M=shm[l], S=shs[l];
        #pragma unroll
        for(int ww=1;ww<16;ww++){
          float m2=shm[ww*64+l], s2=shs[ww*64+l];
          float nm=fmaxf(M,m2);
          S = S*ex2(M-nm) + s2*ex2(m2-nm);
          M = nm;
        }
        __hip_atomic_store(&pb[(size_t)(j&1)*NBLK*KM + (size_t)b*KM + l], packMS(M,S),
                           __ATOMIC_RELAXED, __HIP_MEMORY_SCOPE_AGENT);
      }
      gbar(flags, ++bar, false);
      // redundant cross-block combine (agent-scope loads, LLC-coherent)
      {
        const u64* pbs = pb + (size_t)(j&1)*NBLK*KM;
        float M=-3e38f, S=0.f;
        for (int bb=w; bb<NBLK; bb+=16){
          u64 v = __hip_atomic_load(&pbs[(size_t)bb*KM + l], __ATOMIC_RELAXED, __HIP_MEMORY_SCOPE_AGENT);
          float m2=unpackM(v), s2=unpackS(v);
          float nm=fmaxf(M,m2);
          S = S*ex2(M-nm) + s2*ex2(m2-nm);
          M = nm;
        }
        shm[w*64+l]=M; shs[w*64+l]=S;
        __syncthreads();
        if (t<64){
          float M2=shm[l], S2=shs[l];
          #pragma unroll
          for(int ww=1;ww<16;ww++){
            float m2=shm[ww*64+l], s2=shs[ww*64+l];
            float nm=fmaxf(M2,m2);
            S2 = S2*ex2(M2-nm) + s2*ex2(m2-nm);
            M2 = nm;
          }
          gsh[l] = lq2 - (M2 + lg2(S2));         // g/e in base-2 units
        }
        __syncthreads();
        gl2 = gsh[l];
      }
    }

    // ---- C: T = 2^(logp2 - lse_row + y), into LDS + global copy for the gather ----
    #pragma unroll
    for (int s=0;s<SLOTS;s++){
      int rr = w + 16*s;
      if (rr < nrows){
        int n = n0+rr;
        float c2 = cls[rr*KM+l];
        float y = gl2 - c2;
        float mx = groupmax8(y);
        float s8 = groupsum8(ex2(y-mx));
        float lse = mx + lg2(s8);
        float tv = ex2(logp2 - lse + y);
        cls[rr*KM+l] = tv;
        Tg[(size_t)n*KM+l] = tv;
      }
    }
    gbar(flags, ++bar, true);   // full fence: Tg bulk handoff

    // ---- D: SPMM over own rows into registers (no global CT!) ----
    #pragma unroll
    for (int s=0;s<SLOTS;s++){
      int rr = w + 16*s;
      if (rr < nrows){
        int n = n0+rr;
        int st=estart[n], len=deg[n];
        float acc=0.f;
        int jj=0;
        for (; jj+3<len; jj+=4){
          int d0=sdst[st+jj], d1=sdst[st+jj+1], d2=sdst[st+jj+2], d3=sdst[st+jj+3];
          acc += Tg[(size_t)d0*KM+l]; acc += Tg[(size_t)d1*KM+l];
          acc += Tg[(size_t)d2*KM+l]; acc += Tg[(size_t)d3*KM+l];
        }
        for (; jj<len; jj++) acc += Tg[(size_t)sdst[st+jj]*KM+l];
        ctreg[s]=acc;
      }
    }
    // no barrier: phase A of next outer touches only block-local data;
    // first sinkhorn barrier transitively orders everything.
  }

  // ---- E: fgw reduction (T in LDS, CT in registers) ----
  float mfa=0.f, gwa=0.f;
  #pragma unroll
  for (int s=0;s<SLOTS;s++){
    int rr = w + 16*s;
    if (rr < nrows){
      int n = n0+rr;
      float tv = cls[rr*KM+l];
      float mf = Mf[(size_t)n*KM+l];
      float ct = ctreg[s];
      float c1p=(float)deg[n]*(1.f/NN);
      float dot=0.f;
      #pragma unroll
      for(int m=0;m<MT;m++) dot += __shfl(ct, base+m)*tm[m];
      float tens = c1p + w2q - 2.f*dot;
      mfa += mf*tv; gwa += tens*tv;
    }
  }
  mfa=groupsum8(mfa); gwa=groupsum8(gwa);
  __syncthreads();
  shm[w*64+l]=mfa; shs[w*64+l]=gwa;
  __syncthreads();
  if (t<64 && (l&7)==0){
    float vm=0.f, vg=0.f;
    #pragma unroll
    for(int ww=0;ww<16;ww++){ vm+=shm[ww*64+l]; vg+=shs[ww*64+l]; }
    atomicAdd(&fgwacc[l>>3], vm);
    atomicAdd(&fgwacc[8+(l>>3)], vg);
  }
  gbar(flags, ++bar, false);
  if (b==0 && t<8){
    float fm = __hip_atomic_load(&fgwacc[t],   __ATOMIC_RELAXED, __HIP_MEMORY_SCOPE_AGENT);
    float fg = __hip_atomic_load(&fgwacc[8+t], __ATOMIC_RELAXED, __HIP_MEMORY_SCOPE_AGENT);
    outp[t] = onea*fm + alpha*fg;
  }
}

extern "C" void kernel_launch(void* const* d_in, const int* in_sizes, int n_in,
                              void* d_out, int out_size, void* d_ws, size_t ws_size,
                              hipStream_t stream){
  const float* x    = (const float*)d_in[0];
  const int*   ei   = (const int*)  d_in[1];
  const float* tmpl = (const float*)d_in[2];
  const float* tf   = (const float*)d_in[3];
  const float* q0   = (const float*)d_in[4];
  const float* a0   = (const float*)d_in[5];
  const int* src = ei;
  const int* dst = ei + NE;

  char* ws = (char*)d_ws;
  size_t o=0;
  auto carve = [&](size_t bytes)->void*{ void* p = ws+o; o += (bytes+255)&~(size_t)255; return p; };
  float* Tg    = (float*)carve((size_t)NN*KM*4);
  float* Mf    = (float*)carve((size_t)NN*KM*4);
  int* sdst    = (int*)carve((size_t)NE*4);
  int* rank    = (int*)carve((size_t)NE*4);
  int* deg     = (int*)carve((size_t)NN*4);
  int* estart  = (int*)carve((size_t)NN*4);
  int* bsum    = (int*)carve(512*4);
  int* boff    = (int*)carve(512*4);
  float* qbuf  = (float*)carve(512*4);
  float* absum = (float*)carve(64*4);
  float* fgwacc= (float*)carve(64*4);
  u32* flags   = (u32*)carve(NBLK*4);
  u64* pb      = (u64*)carve((size_t)2*NBLK*KM*8);

  hipMemsetAsync(deg,    0, NN*4,    stream);
  hipMemsetAsync(absum,  0, 64*4,    stream);
  hipMemsetAsync(fgwacc, 0, 64*4,    stream);
  hipMemsetAsync(flags,  0, NBLK*4,  stream);

  k_prep<<<1,64,0,stream>>>(tmpl, tf, q0, a0, qbuf);
  k_deg<<<(NE+255)/256,256,0,stream>>>(src, deg, rank);
  k_scan1<<<SCAN_B,256,0,stream>>>(deg, estart, bsum);
  k_scan2<<<1,512,0,stream>>>(bsum, boff);
  k_scan3<<<SCAN_B,256,0,stream>>>(estart, boff);
  k_scatter<<<(NE+255)/256,256,0,stream>>>(src, dst, estart, rank, sdst);
  k_mfeat<<<512,256,0,stream>>>(x, tf, Mf);

  k_main<<<NBLK,1024,0,stream>>>(tmpl, qbuf, deg, estart, sdst, Mf,
                                 Tg, pb, absum, fgwacc, flags, (float*)d_out);
}

// Round 11
// 2999.223 us; speedup vs baseline: 1.8050x; 1.0442x over previous
//
#include <hip/hip_runtime.h>
#include <math.h>

#define NN 100000
#define NE 1600000
#define NFD 128
#define KT 8
#define MT 8
#define KM 64
#define NOUT 5
#define NSK 20
#define EPSR 0.05f

#define NBLK 248          // persistent blocks, 1 per CU (103KB LDS forces 1/CU)
#define RPBM 404          // ceil(NN/NBLK)
#define WSLOTS 26         // ceil(RPBM/16)  (w,l)-layout loops
#define KSLOTS 4          // ceil(RPBM/128) rows/thread in k-layout
#define MSST 130          // (M,S) scratch stride (bank-spread)
#define SCAN_B 391        // ceil(NN/256)

typedef unsigned int u32;
typedef unsigned long long u64;

__device__ __forceinline__ float groupmax8(float v){
  v = fmaxf(v, __shfl_xor(v,1));
  v = fmaxf(v, __shfl_xor(v,2));
  v = fmaxf(v, __shfl_xor(v,4));
  return v;
}
__device__ __forceinline__ float groupsum8(float v){
  v += __shfl_xor(v,1);
  v += __shfl_xor(v,2);
  v += __shfl_xor(v,4);
  return v;
}
__device__ __forceinline__ float ex2(float x){ return __builtin_amdgcn_exp2f(x); }
__device__ __forceinline__ float lg2(float x){ return __builtin_amdgcn_logf(x); }   // log2

__device__ __forceinline__ u64 packMS(float M, float S){
  return ((u64)__builtin_bit_cast(u32, S) << 32) | (u64)__builtin_bit_cast(u32, M);
}
__device__ __forceinline__ float unpackM(u64 v){ return __builtin_bit_cast(float, (u32)(v & 0xffffffffull)); }
__device__ __forceinline__ float unpackS(u64 v){ return __builtin_bit_cast(float, (u32)(v >> 32)); }

// online-LSE combine with a SINGLE exp2: (M,S) <- (M,S) (+) (m2,s2)
__device__ __forceinline__ void lsecomb(float& M, float& S, float m2, float s2){
  float d = m2 - M;
  float p = ex2(-fabsf(d));
  S = (d <= 0.f) ? fmaf(s2, p, S) : fmaf(S, p, s2);
  M = fmaxf(M, m2);
}

// Contention-free grid barrier (per-block monotonic epoch flags).
__device__ __forceinline__ void gbar(u32* __restrict__ flags, u32 tgt, bool full){
  asm volatile("s_waitcnt vmcnt(0)" ::: "memory");
  __syncthreads();
  const int t = threadIdx.x;
  if (t==0){
    if (full) __builtin_amdgcn_fence(__ATOMIC_RELEASE, "agent");
    __hip_atomic_store(&flags[blockIdx.x], tgt, __ATOMIC_RELAXED, __HIP_MEMORY_SCOPE_AGENT);
  }
  if (t < NBLK){
    int sp = 0;
    while (__hip_atomic_load(&flags[t], __ATOMIC_RELAXED, __HIP_MEMORY_SCOPE_AGENT) < tgt){
      __builtin_amdgcn_s_sleep(2);
      if (++sp > (1<<20)) break;
    }
  }
  __syncthreads();
  if (full){
    if (t==0) __builtin_amdgcn_fence(__ATOMIC_ACQUIRE, "agent");
    __syncthreads();
  }
}

// ---------------- small precompute: q, logq, w2q, tq, alpha ----------------
__global__ void k_prep(const float* __restrict__ tmpl, const float* __restrict__ tf,
                       const float* __restrict__ q0, const float* __restrict__ a0,
                       float* __restrict__ qbuf){
  int l = threadIdx.x; // l = k*8+i
  float z = q0[l];
  float mx = groupmax8(z);
  float ex = expf(z-mx);
  float s  = groupsum8(ex);
  float q  = ex/s;
  float lq = (z-mx) - logf(s);
  float w2q=0.f, tq=0.f;
  int base = l & 56;
  #pragma unroll
  for (int m=0;m<MT;m++){
    float qm = __shfl(q, base+m);
    float tm = tmpl[l*MT+m];
    w2q += tm*tm*qm;
    tq  += tm*qm;
  }
  qbuf[l]=q; qbuf[64+l]=lq; qbuf[128+l]=w2q; qbuf[192+l]=tq;
  if (l==0) qbuf[320] = 1.f/(1.f+expf(-a0[0]));
}

// ---------------- edge CSR build ----------------
__global__ void k_deg(const int* __restrict__ src, int* __restrict__ deg, int* __restrict__ rank){
  int i = blockIdx.x*blockDim.x + threadIdx.x;
  if (i < NE) rank[i] = atomicAdd(&deg[src[i]], 1);
}
__global__ void k_scan1(const int* __restrict__ deg, int* __restrict__ estart, int* __restrict__ bsum){
  __shared__ int sh[256];
  int t = threadIdx.x, b = blockIdx.x, i = b*256+t;
  int v = (i<NN)? deg[i] : 0;
  sh[t] = v; __syncthreads();
  for (int off=1; off<256; off<<=1){
    int x = (t>=off)? sh[t-off] : 0;
    __syncthreads();
    sh[t] += x;
    __syncthreads();
  }
  if (i<NN) estart[i] = sh[t]-v;
  if (t==255) bsum[b] = sh[t];
}
__global__ void k_scan2(const int* __restrict__ bsum, int* __restrict__ boff){
  __shared__ int sh[512];
  int t = threadIdx.x;
  int v = (t<SCAN_B)? bsum[t] : 0;
  sh[t]=v; __syncthreads();
  for (int off=1; off<512; off<<=1){
    int x = (t>=off)? sh[t-off] : 0;
    __syncthreads();
    sh[t]+=x;
    __syncthreads();
  }
  if (t<SCAN_B) boff[t] = sh[t]-v;
}
__global__ void k_scan3(int* __restrict__ estart, const int* __restrict__ boff){
  int i = blockIdx.x*256 + threadIdx.x;
  if (i<NN) estart[i] += boff[blockIdx.x];
}
__global__ void k_scatter(const int* __restrict__ src, const int* __restrict__ dst,
                          const int* __restrict__ estart, const int* __restrict__ rank,
                          int* __restrict__ sdst){
  int i = blockIdx.x*blockDim.x + threadIdx.x;
  if (i < NE){
    sdst[estart[src[i]] + rank[i]] = dst[i];
  }
}

// ---------------- Mfeat ----------------
__global__ void __launch_bounds__(256,2) k_mfeat(const float* __restrict__ x,
                                                 const float* __restrict__ tf,
                                                 float* __restrict__ Mf){
  int t=threadIdx.x, w=t>>6, l=t&63;
  float tfr[NFD];
  #pragma unroll
  for (int j=0;j<NFD;j++) tfr[j]=tf[l*NFD+j];
  float tt=0.f;
  #pragma unroll
  for (int j=0;j<NFD;j++) tt += tfr[j]*tfr[j];
  int gw=blockIdx.x*4+w, nw=gridDim.x*4;
  for (int n=gw; n<NN; n+=nw){
    float x0=x[(size_t)n*NFD+l], x1=x[(size_t)n*NFD+64+l];
    float acc=0.f;
    #pragma unroll
    for (int j=0;j<64;j++){
      float xa=__builtin_bit_cast(float, __builtin_amdgcn_readlane(__builtin_bit_cast(int,x0), j));
      float xb=__builtin_bit_cast(float, __builtin_amdgcn_readlane(__builtin_bit_cast(int,x1), j));
      acc = fmaf(xa, tfr[j], acc);
      acc = fmaf(xb, tfr[64+j], acc);
    }
    float xx=x0*x0+x1*x1;
    xx+=__shfl_xor(xx,1); xx+=__shfl_xor(xx,2); xx+=__shfl_xor(xx,4);
    xx+=__shfl_xor(xx,8); xx+=__shfl_xor(xx,16); xx+=__shfl_xor(xx,32);
    Mf[(size_t)n*KM+l]=xx+tt-2.f*acc;
  }
}

// swizzled ctls index for the (w,l) layout
__device__ __forceinline__ int cidx(int rr, int l){
  return rr*64 + ((((l>>3) ^ (rr&7))<<3) | (l&7));
}

// ---------------- persistent fused kernel ----------------
__global__ void __launch_bounds__(1024,4) k_main(
    const float* __restrict__ tmpl, const float* __restrict__ qbuf,
    const int* __restrict__ deg, const int* __restrict__ estart,
    const int* __restrict__ sdst, const float* __restrict__ Mf,
    float* __restrict__ Tg, u64* __restrict__ pb,
    float* __restrict__ pbabs, float* __restrict__ pbfgw,
    u32* __restrict__ flags, float* __restrict__ outp)
{
  __shared__ __align__(16) float LB[RPBM*KM];   // 103KB multi-purpose (CT/T-stage | (M,S) scratch | trees)
  __shared__ __align__(16) float gsh[64];
  __shared__ float lq2sh[64];
  __shared__ float tlsh[512];
  __shared__ float esh[8];
  __shared__ float wred[16];
  __shared__ float wred2[16];

  const int t = threadIdx.x, b = blockIdx.x;
  const int w = t>>6, l = t&63;
  const int k = t>>7, j2 = t&127;
  const int n0 = b*RPBM;
  const int nrows = min(RPBM, NN-n0);
  const float LOG2E = 1.4426950408889634f;
  const float logp2 = -log2f((float)NN);
  u32 bar = 0;

  if (t<64) lq2sh[t] = qbuf[64+t]*LOG2E;
  if (t<512) tlsh[t] = tmpl[t];
  float w2q8[8], tq8[8];
  #pragma unroll
  for (int m=0;m<8;m++){ w2q8[m]=qbuf[128+k*8+m]; tq8[m]=qbuf[192+k*8+m]; }
  const float alpha=qbuf[320], onea=1.f-alpha;
  __syncthreads();

  float c2[KSLOTS][8];   // cost (base-2/e units), later T
  float g8[8];
  #pragma unroll
  for (int m=0;m<8;m++) g8[m]=0.f;

  for (int it=0; it<NOUT; ++it){
    // ---- A: cost into registers (+|cost| partial) ----
    float absacc = 0.f;
    #pragma unroll
    for (int s=0;s<KSLOTS;s++){
      int rr = j2 + 128*s;
      if (rr < nrows){
        int n = n0+rr;
        float c1p = (float)deg[n]*(1.f/NN);
        float mv[8];
        { const float4* mp = (const float4*)&Mf[(size_t)n*KM + k*8];
          *(float4*)&mv[0] = mp[0]; *(float4*)&mv[4] = mp[1]; }
        float ct[8];
        if (it>0){
          const float4* cp = (const float4*)&LB[rr*64 + ((k ^ (rr&7))<<3)];
          *(float4*)&ct[0] = cp[0]; *(float4*)&ct[4] = cp[1];
        }
        #pragma unroll
        for (int p=0;p<8;p++){
          float gwt;
          if (it==0){
            gwt = c1p + w2q8[p] - 2.f*c1p*tq8[p];       // CT0 = C1p*q analytically
          } else {
            float dot=0.f;
            #pragma unroll
            for (int m=0;m<8;m++) dot = fmaf(ct[m], tlsh[k*64+p*8+m], dot);
            gwt = c1p + w2q8[p] - 2.f*dot;
          }
          float c = alpha*gwt + onea*mv[p];
          c2[s][p] = c;
          absacc += fabsf(c);
        }
      }
    }
    // per-k block sum of |cost| (wave is k-uniform)
    #pragma unroll
    for (int d=1; d<64; d<<=1) absacc += __shfl_xor(absacc, d);
    __syncthreads();                       // CT in LB now dead
    if ((t&63)==0) wred[w] = absacc;
    __syncthreads();
    if (t<8)
      __hip_atomic_store(&pbabs[(size_t)(it*NBLK+b)*8 + t], wred[2*t]+wred[2*t+1],
                         __ATOMIC_RELAXED, __HIP_MEMORY_SCOPE_AGENT);
    gbar(flags, ++bar, false);
    { // all blocks deterministically reduce 248x8 partials -> e per k
      int k0 = t&7, i = t>>3;              // i in 0..127
      float v = 0.f;
      if (i < NBLK)
        v += __hip_atomic_load(&pbabs[(size_t)(it*NBLK+i)*8+k0], __ATOMIC_RELAXED, __HIP_MEMORY_SCOPE_AGENT);
      if (i+128 < NBLK)
        v += __hip_atomic_load(&pbabs[(size_t)(it*NBLK+i+128)*8+k0], __ATOMIC_RELAXED, __HIP_MEMORY_SCOPE_AGENT);
      LB[i*9+k0] = v;
      __syncthreads();
      #pragma unroll
      for (int off=64; off>=1; off>>=1){
        if (i < off) LB[i*9+k0] += LB[(i+off)*9+k0];
        __syncthreads();
      }
      if (t<8) esh[t] = EPSR * LB[t] * (1.f/((float)NN*MT));
      __syncthreads();
    }
    {
      float ie2 = LOG2E / esh[k];
      #pragma unroll
      for (int s=0;s<KSLOTS;s++)
        #pragma unroll
        for (int p=0;p<8;p++) c2[s][p] *= ie2;
    }

    // ---- B: 20 sinkhorn iterations, zero DS in element loop ----
    for (int jj=0; jj<NSK; ++jj){
      float M8[8], S8[8];
      #pragma unroll
      for (int m=0;m<8;m++){ M8[m]=-3e38f; S8[m]=0.f; }
      if (jj==0){
        #pragma unroll
        for (int s=0;s<KSLOTS;s++){
          int rr = j2+128*s;
          if (rr<nrows){
            #pragma unroll
            for (int m=0;m<8;m++) lsecomb(M8[m], S8[m], -c2[s][m], 1.f);  // f0 = 0
          }
        }
      } else {
        #pragma unroll
        for (int s=0;s<KSLOTS;s++){
          int rr = j2+128*s;
          if (rr<nrows){
            float y[8];
            #pragma unroll
            for (int m=0;m<8;m++) y[m] = g8[m] - c2[s][m];
            float mx = fmaxf(fmaxf(fmaxf(y[0],y[1]),fmaxf(y[2],y[3])),
                             fmaxf(fmaxf(y[4],y[5]),fmaxf(y[6],y[7])));
            float sr = 0.f;
            #pragma unroll
            for (int m=0;m<8;m++) sr += ex2(y[m]-mx);
            float base = logp2 - (mx + lg2(sr));        // f/e (base2)
            #pragma unroll
            for (int m=0;m<8;m++) lsecomb(M8[m], S8[m], base - c2[s][m], 1.f);
          }
        }
      }
      // stage 1: write per-thread (M,S) to padded scratch
      float* msM = LB;
      float* msS = LB + 64*MSST;
      #pragma unroll
      for (int m=0;m<8;m++){
        msM[(k*8+m)*MSST + j2] = M8[m];
        msS[(k*8+m)*MSST + j2] = S8[m];
      }
      __syncthreads();
      // stage 2: 16 threads per (k,m) column
      {
        int c = t>>4, sub = t&15;
        float M=-3e38f, S=0.f;
        #pragma unroll
        for (int i=0;i<8;i++){
          int ji = sub + 16*i;
          lsecomb(M, S, msM[c*MSST+ji], msS[c*MSST+ji]);
        }
        #pragma unroll
        for (int d=1; d<16; d<<=1){
          float m2 = __shfl_xor(M, d);
          float s2 = __shfl_xor(S, d);
          lsecomb(M, S, m2, s2);
        }
        if (sub==0)
          __hip_atomic_store(&pb[(size_t)(jj&1)*NBLK*KM + (size_t)b*KM + c], packMS(M,S),
                             __ATOMIC_RELAXED, __HIP_MEMORY_SCOPE_AGENT);
      }
      gbar(flags, ++bar, false);
      // cross-block combine (batched independent loads)
      {
        const u64* pbs = pb + (size_t)(jj&1)*NBLK*KM;
        int c = t&63, ch = t>>6;           // ch 0..15 -> blocks ch*16..ch*16+15
        float M=-3e38f, S=0.f;
        #pragma unroll
        for (int half=0; half<2; half++){
          u64 vv[8];
          #pragma unroll
          for (int i=0;i<8;i++){
            int bb = ch*16 + half*8 + i;
            vv[i] = (bb<NBLK) ? __hip_atomic_load(&pbs[(size_t)bb*KM + c], __ATOMIC_RELAXED, __HIP_MEMORY_SCOPE_AGENT)
                              : packMS(-3e38f, 0.f);
          }
          #pragma unroll
          for (int i=0;i<8;i++) lsecomb(M, S, unpackM(vv[i]), unpackS(vv[i]));
        }
        u64* xch = (u64*)LB;
        xch[c*16 + ch] = packMS(M,S);
        __syncthreads();
        if (t<64){
          float M2=-3e38f, S2=0.f;
          #pragma unroll
          for (int i=0;i<16;i++){
            u64 v2 = xch[t*16+i];
            lsecomb(M2, S2, unpackM(v2), unpackS(v2));
          }
          gsh[t] = lq2sh[t] - (M2 + lg2(S2));   // g/e, base-2
        }
        __syncthreads();
      }
      #pragma unroll
      for (int m=0;m<8;m++) g8[m] = gsh[k*8+m];
    }

    // ---- C: T = 2^(f/e + g/e - c2) into regs, stage to LB, coalesced copy to Tg ----
    #pragma unroll
    for (int s=0;s<KSLOTS;s++){
      int rr = j2+128*s;
      if (rr<nrows){
        float y[8];
        #pragma unroll
        for (int m=0;m<8;m++) y[m] = g8[m] - c2[s][m];
        float mx = fmaxf(fmaxf(fmaxf(y[0],y[1]),fmaxf(y[2],y[3])),
                         fmaxf(fmaxf(y[4],y[5]),fmaxf(y[6],y[7])));
        float sr = 0.f;
        #pragma unroll
        for (int m=0;m<8;m++) sr += ex2(y[m]-mx);
        float base = logp2 - (mx + lg2(sr));
        #pragma unroll
        for (int m=0;m<8;m++) c2[s][m] = ex2(base + y[m]);
        float4* dp = (float4*)&LB[rr*64 + ((k ^ (rr&7))<<3)];
        dp[0] = make_float4(c2[s][0],c2[s][1],c2[s][2],c2[s][3]);
        dp[1] = make_float4(c2[s][4],c2[s][5],c2[s][6],c2[s][7]);
      }
    }
    __syncthreads();
    for (int s2=0;s2<WSLOTS;s2++){
      int rr2 = w + 16*s2;
      if (rr2<nrows) Tg[(size_t)(n0+rr2)*KM + l] = LB[cidx(rr2,l)];
    }
    gbar(flags, ++bar, true);              // full fence: Tg bulk handoff

    // ---- D: SPMM (coalesced row gathers) into LB (swizzled CT) ----
    for (int s2=0;s2<WSLOTS;s2++){
      int rr2 = w + 16*s2;
      if (rr2<nrows){
        int n = n0+rr2;
        int st=estart[n], len=deg[n];
        float acc=0.f;
        int e=0;
        for (; e+3<len; e+=4){
          int d0=sdst[st+e], d1=sdst[st+e+1], d2=sdst[st+e+2], d3=sdst[st+e+3];
          acc += Tg[(size_t)d0*KM+l]; acc += Tg[(size_t)d1*KM+l];
          acc += Tg[(size_t)d2*KM+l]; acc += Tg[(size_t)d3*KM+l];
        }
        for (; e<len; e++) acc += Tg[(size_t)sdst[st+e]*KM+l];
        LB[cidx(rr2,l)] = acc;
      }
    }
    __syncthreads();
  }

  // ---- E: fgw reduction (T in regs, CT in LB, per-k sums) ----
  float mfacc=0.f, gwacc=0.f;
  #pragma unroll
  for (int s=0;s<KSLOTS;s++){
    int rr = j2+128*s;
    if (rr<nrows){
      int n = n0+rr;
      float c1p = (float)deg[n]*(1.f/NN);
      float mv[8];
      { const float4* mp = (const float4*)&Mf[(size_t)n*KM + k*8];
        *(float4*)&mv[0]=mp[0]; *(float4*)&mv[4]=mp[1]; }
      float ct[8];
      { const float4* cp = (const float4*)&LB[rr*64 + ((k ^ (rr&7))<<3)];
        *(float4*)&ct[0]=cp[0]; *(float4*)&ct[4]=cp[1]; }
      #pragma unroll
      for (int p=0;p<8;p++){
        float dot=0.f;
        #pragma unroll
        for (int m=0;m<8;m++) dot = fmaf(ct[m], tlsh[k*64+p*8+m], dot);
        float tens = c1p + w2q8[p] - 2.f*dot;
        mfacc = fmaf(mv[p], c2[s][p], mfacc);
        gwacc = fmaf(tens, c2[s][p], gwacc);
      }
    }
  }
  #pragma unroll
  for (int d=1; d<64; d<<=1){ mfacc += __shfl_xor(mfacc,d); gwacc += __shfl_xor(gwacc,d); }
  __syncthreads();
  if ((t&63)==0){ wred[w]=mfacc; wred2[w]=gwacc; }
  __syncthreads();
  if (t<8){
    __hip_atomic_store(&pbfgw[((size_t)b*8+t)*2+0], wred[2*t]+wred[2*t+1],
                       __ATOMIC_RELAXED, __HIP_MEMORY_SCOPE_AGENT);
    __hip_atomic_store(&pbfgw[((size_t)b*8+t)*2+1], wred2[2*t]+wred2[2*t+1],
                       __ATOMIC_RELAXED, __HIP_MEMORY_SCOPE_AGENT);
  }
  gbar(flags, ++bar, false);
  if (b==0){
    int k0 = t&7, i = t>>3;
    float vm=0.f, vg=0.f;
    if (i < NBLK){
      vm += __hip_atomic_load(&pbfgw[((size_t)i*8+k0)*2+0], __ATOMIC_RELAXED, __HIP_MEMORY_SCOPE_AGENT);
      vg += __hip_atomic_load(&pbfgw[((size_t)i*8+k0)*2+1], __ATOMIC_RELAXED, __HIP_MEMORY_SCOPE_AGENT);
    }
    if (i+128 < NBLK){
      vm += __hip_atomic_load(&pbfgw[((size_t)(i+128)*8+k0)*2+0], __ATOMIC_RELAXED, __HIP_MEMORY_SCOPE_AGENT);
      vg += __hip_atomic_load(&pbfgw[((size_t)(i+128)*8+k0)*2+1], __ATOMIC_RELAXED, __HIP_MEMORY_SCOPE_AGENT);
    }
    LB[i*9+k0] = vm; LB[1280 + i*9+k0] = vg;
    __syncthreads();
    #pragma unroll
    for (int off=64; off>=1; off>>=1){
      if (i < off){
        LB[i*9+k0]      += LB[(i+off)*9+k0];
        LB[1280+i*9+k0] += LB[1280+(i+off)*9+k0];
      }
      __syncthreads();
    }
    if (t<8) outp[t] = onea*LB[t] + alpha*LB[1280+t];
  }
}

extern "C" void kernel_launch(void* const* d_in, const int* in_sizes, int n_in,
                              void* d_out, int out_size, void* d_ws, size_t ws_size,
                              hipStream_t stream){
  const float* x    = (const float*)d_in[0];
  const int*   ei   = (const int*)  d_in[1];
  const float* tmpl = (const float*)d_in[2];
  const float* tf   = (const float*)d_in[3];
  const float* q0   = (const float*)d_in[4];
  const float* a0   = (const float*)d_in[5];
  const int* src = ei;
  const int* dst = ei + NE;

  char* ws = (char*)d_ws;
  size_t o=0;
  auto carve = [&](size_t bytes)->void*{ void* p = ws+o; o += (bytes+255)&~(size_t)255; return p; };
  float* Tg    = (float*)carve((size_t)NN*KM*4);
  float* Mf    = (float*)carve((size_t)NN*KM*4);
  int* sdst    = (int*)carve((size_t)NE*4);
  int* rank    = (int*)carve((size_t)NE*4);
  int* deg     = (int*)carve((size_t)NN*4);
  int* estart  = (int*)carve((size_t)NN*4);
  int* bsum    = (int*)carve(512*4);
  int* boff    = (int*)carve(512*4);
  float* qbuf  = (float*)carve(512*4);
  u32* flags   = (u32*)carve(NBLK*4);
  u64* pb      = (u64*)carve((size_t)2*NBLK*KM*8);
  float* pbabs = (float*)carve((size_t)NOUT*NBLK*8*4);
  float* pbfgw = (float*)carve((size_t)NBLK*16*4);

  hipMemsetAsync(deg,   0, NN*4,   stream);
  hipMemsetAsync(flags, 0, NBLK*4, stream);

  k_prep<<<1,64,0,stream>>>(tmpl, tf, q0, a0, qbuf);
  k_deg<<<(NE+255)/256,256,0,stream>>>(src, deg, rank);
  k_scan1<<<SCAN_B,256,0,stream>>>(deg, estart, bsum);
  k_scan2<<<1,512,0,stream>>>(bsum, boff);
  k_scan3<<<SCAN_B,256,0,stream>>>(estart, boff);
  k_scatter<<<(NE+255)/256,256,0,stream>>>(src, dst, estart, rank, sdst);
  k_mfeat<<<512,256,0,stream>>>(x, tf, Mf);

  k_main<<<NBLK,1024,0,stream>>>(tmpl, qbuf, deg, estart, sdst, Mf,
                                 Tg, pb, pbabs, pbfgw, flags, (float*)d_out);
}